// Round 1
// baseline (84.624 us; speedup 1.0000x reference)
//
#include <hip/hip_runtime.h>

// BilateralBlur 7x7, sigma_color=0.1 (l1 color distance), sigma_space=1.5,
// reflect padding. Input/Output: (B=4, C=3, H=512, W=512) float32.
//
// Design notes:
// - One thread per output pixel; 32x8 block; LDS tile (8+6)x(32+6) with the
//   3 channels interleaved in a 16B slot -> each tap is ONE ds_read_b128.
// - Space kernel is used UNNORMALIZED: the per-axis normalization is a
//   constant factor on every tap weight and cancels in sum(w*p)/sum(w).
// - Reflect index: i<0 -> -i ; i>=N -> 2N-2-i (jnp.pad mode='reflect').

constexpr int KR  = 3;            // kernel radius (7x7)
constexpr int CH  = 3;
constexpr int IMH = 512, IMW = 512;
constexpr int BX  = 32, BY = 8;   // 256 threads
constexpr int TW  = BX + 2 * KR;  // 38
constexpr int TH  = BY + 2 * KR;  // 14

__global__ __launch_bounds__(BX * BY)
void bilateral7_kernel(const float* __restrict__ in, float* __restrict__ out) {
    __shared__ float tile[TH][TW][4];   // [y][x][c], c=3 slot unused (pad to 16B)

    const int tx = threadIdx.x, ty = threadIdx.y;
    const int x0 = blockIdx.x * BX, y0 = blockIdx.y * BY;
    const int b  = blockIdx.z;
    const float* __restrict__ inb = in + (size_t)b * CH * IMH * IMW;

    // Cooperative tile load with reflect indexing. ix fastest -> coalesced.
    const int tid = ty * BX + tx;
    for (int idx = tid; idx < CH * TH * TW; idx += BX * BY) {
        int c   = idx / (TH * TW);
        int r   = idx - c * (TH * TW);
        int iy  = r / TW;
        int ix  = r - iy * TW;
        int gy  = y0 + iy - KR;
        int gx  = x0 + ix - KR;
        gy = gy < 0 ? -gy : (gy >= IMH ? 2 * IMH - 2 - gy : gy);
        gx = gx < 0 ? -gx : (gx >= IMW ? 2 * IMW - 2 - gx : gx);
        tile[iy][ix][c] = inb[(c * IMH + gy) * IMW + gx];
    }
    __syncthreads();

    // Unnormalized 1D spatial gaussian, sigma=1.5: exp(-d^2/4.5), d=-3..3
    const float w1d[7] = {0.13533528f, 0.41111229f, 0.80073744f, 1.0f,
                          0.80073744f, 0.41111229f, 0.13533528f};

    const float4 ctr = *(const float4*)&tile[ty + KR][tx + KR][0];

    float acc0 = 0.f, acc1 = 0.f, acc2 = 0.f, wsum = 0.f;
    #pragma unroll
    for (int dy = 0; dy < 7; ++dy) {
        const float wy = w1d[dy];
        #pragma unroll
        for (int dx = 0; dx < 7; ++dx) {
            const float4 p = *(const float4*)&tile[ty + dy][tx + dx][0];
            const float l1 = fabsf(p.x - ctr.x) + fabsf(p.y - ctr.y) + fabsf(p.z - ctr.z);
            const float wgt = wy * w1d[dx] * __expf(-50.0f * l1 * l1);
            acc0 = fmaf(p.x, wgt, acc0);
            acc1 = fmaf(p.y, wgt, acc1);
            acc2 = fmaf(p.z, wgt, acc2);
            wsum += wgt;
        }
    }

    const float inv = 1.0f / wsum;
    const int y = y0 + ty, x = x0 + tx;
    const size_t base = (size_t)b * CH * IMH * IMW + (size_t)y * IMW + x;
    out[base + 0 * (size_t)IMH * IMW] = acc0 * inv;
    out[base + 1 * (size_t)IMH * IMW] = acc1 * inv;
    out[base + 2 * (size_t)IMH * IMW] = acc2 * inv;
}

extern "C" void kernel_launch(void* const* d_in, const int* in_sizes, int n_in,
                              void* d_out, int out_size, void* d_ws, size_t ws_size,
                              hipStream_t stream) {
    const float* in  = (const float*)d_in[0];
    float*       out = (float*)d_out;
    const int B = in_sizes[0] / (CH * IMH * IMW);   // 4
    dim3 grid(IMW / BX, IMH / BY, B);               // (16, 64, 4)
    dim3 block(BX, BY, 1);
    bilateral7_kernel<<<grid, block, 0, stream>>>(in, out);
}